// Round 2
// 948.986 us; speedup vs baseline: 1.0484x; 1.0484x over previous
//
#include <hip/hip_runtime.h>

// ---------------------------------------------------------------------------
// NewCNNEncoder: one-hot(x[B,25]) -> {full, hori, vert} branches -> cat[B,960]
//                -> big GEMM [B,960]x[960,1600] -> lrelu -> out fp32.
//
// Decomposition:
//  P   prep_kernel   : bf16-transpose/permute W_out & W_pf; build U tables
//  A   build_afull   : a_full[B,448] = lrelu(depthwise_full + b_df)  (bf16)
//  G1  gemm_bt<448,0>: cat[:,0:320]  = lrelu(a_full @ W_pf^T + b_pf) (bf16 MFMA)
//  HV  hv_kernel     : cat[:,320:960] via U-table lookups (exact fp32 math)
//  G2  gemm_bt<960,1>: out = lrelu(cat @ W_out'^T + b_out)           (bf16 MFMA)
//
// R1: chunk-contiguous XCD swizzle (T1) on both GEMMs. Measured fetch was
//     ~8x A-matrix (1.04 GB vs 126 MB ideal): consecutive N-tiles of one
//     M-band round-robin onto all 8 XCD L2s. Remap so each XCD owns a
//     contiguous chunk of the grid -> A-band fetched once per XCD, reused
//     by its 13 (G2) / 3 (G1) N-tiles.
// R2: identical resubmit (R1 bench was an infra failure, never measured).
// ---------------------------------------------------------------------------

typedef __bf16 bf16;
typedef bf16  bf16x8 __attribute__((ext_vector_type(8)));
typedef float f32x4  __attribute__((ext_vector_type(4)));

__device__ __forceinline__ float lrelu(float v) { return v > 0.f ? v : 0.01f * v; }

// async global->LDS, 16B per lane; LDS dest must be wave-uniform base + lane*16
__device__ __forceinline__ void gl2lds16(const void* g, void* l) {
  __builtin_amdgcn_global_load_lds(
      (__attribute__((address_space(1))) void*)const_cast<void*>(g),
      (__attribute__((address_space(3))) void*)l, 16, 0, 0);
}

// T1 chunk-contiguous XCD swizzle (m204 bijective form; hw assigns launch-linear
// round-robin to XCDs, so xcd = linear%8; give each XCD a contiguous logical
// chunk so same-M-band tiles colocate in one XCD's L2).
__device__ __forceinline__ void xcd_remap(int& mt, int& nt) {
  const int nxt    = gridDim.x;
  const int nwg    = gridDim.x * gridDim.y;
  const int linear = blockIdx.y * gridDim.x + blockIdx.x;
  const int xcd = linear & 7, pos = linear >> 3;
  const int q = nwg >> 3, r = nwg & 7;
  const int logical = (xcd < r ? xcd * (q + 1) : r * (q + 1) + (xcd - r) * q) + pos;
  mt = logical / nxt;
  nt = logical - mt * nxt;
}

// ---------------------------------------------------------------------------
// Prep: weight conversion + U tables
//   WbOT [1664][960] bf16 : W_out permuted (k = cat order) & transposed, n-major
//   WbPF [384][448]  bf16 : W_pf transposed+padded, n-major
//   Uh/Uv [17][32][64] f32: U'[c][mask][o]; slot [0][0][o] holds the base term
// ---------------------------------------------------------------------------
__device__ void compute_U(float* __restrict__ U,
                          const float* __restrict__ Wd, const float* __restrict__ bd,
                          const float* __restrict__ Wp, const float* __restrict__ bp,
                          int c, int mask, int o) {
  float val;
  if (mask == 0) {
    if (c == 0) {  // base[o] = bp[o] + sum_cc sum_m Wp[o,cc*16+m]*lrelu(bd)
      float s = bp[o];
      for (int cc = 0; cc < 17; cc++)
        for (int m = 0; m < 16; m++)
          s += Wp[o * 272 + cc * 16 + m] * lrelu(bd[cc * 16 + m]);
      val = s;
    } else {
      val = 0.f;
    }
  } else {
    float s = 0.f;
    #pragma unroll
    for (int m = 0; m < 16; m++) {
      float z = bd[c * 16 + m];
      #pragma unroll
      for (int j = 0; j < 5; j++)
        if ((mask >> j) & 1) z += Wd[c * 80 + m * 5 + j];
      s += Wp[o * 272 + c * 16 + m] * (lrelu(z) - lrelu(bd[c * 16 + m]));
    }
    val = s;
  }
  U[(c * 32 + mask) * 64 + o] = val;
}

__global__ __launch_bounds__(256) void prep_kernel(
    const float* __restrict__ W_pf,
    const float* __restrict__ W_dh, const float* __restrict__ b_dh,
    const float* __restrict__ W_ph, const float* __restrict__ b_ph,
    const float* __restrict__ W_dv, const float* __restrict__ b_dv,
    const float* __restrict__ W_pv, const float* __restrict__ b_pv,
    const float* __restrict__ W_out,
    bf16* __restrict__ WbOT, bf16* __restrict__ WbPF,
    float* __restrict__ Uh, float* __restrict__ Uv) {
  int id = blockIdx.x * 256 + threadIdx.x;

  if (id < 1664 * 960) {  // WbOT[n][k]
    int n = id / 960, k = id % 960;
    float v = 0.f;
    if (n < 1600) {
      int src;
      if (k < 320)      src = n * 960 + (k / 5) * 15 + (k % 5);            // full: j=k -> (c2=k/5, l=k%5)
      else if (k < 640) { int kk = k - 320; src = n * 960 + (kk & 63) * 15 + 5  + (kk >> 6); }  // hori
      else              { int kk = k - 640; src = n * 960 + (kk & 63) * 15 + 10 + (kk >> 6); }  // vert
      v = W_out[src];
    }
    WbOT[id] = (bf16)v;
    return;
  }
  id -= 1664 * 960;

  if (id < 384 * 448) {  // WbPF[n][k]
    int n = id / 448, k = id % 448;
    float v = (n < 320 && k < 425) ? W_pf[n * 425 + k] : 0.f;
    WbPF[id] = (bf16)v;
    return;
  }
  id -= 384 * 448;

  if (id < 17 * 32 * 64) {
    int o = id & 63, rest = id >> 6;
    compute_U(Uh, W_dh, b_dh, W_ph, b_ph, rest >> 5, rest & 31, o);
    return;
  }
  id -= 17 * 32 * 64;

  if (id < 17 * 32 * 64) {
    int o = id & 63, rest = id >> 6;
    compute_U(Uv, W_dv, b_dv, W_pv, b_pv, rest >> 5, rest & 31, o);
  }
}

// ---------------------------------------------------------------------------
// build_afull: a_full[b][c*25+m] = lrelu( b_df[c*25+m] + sum_{l: x[b,l]==c} W_df[c,m,l] )
// 64 samples/block; lane = sample, waves iterate roles (c=0..16, 17=pad-zero).
// Accumulate rows in padded LDS, then one coalesced 16B-vector copy-out.
// ---------------------------------------------------------------------------
#define AF_PAD 456  // LDS row stride (bf16 elems); 456 -> 8-way max bank conflict

__global__ __launch_bounds__(256) void build_afull(
    const int* __restrict__ x, const float* __restrict__ W_df,
    const float* __restrict__ b_df, bf16* __restrict__ a_full) {
  __shared__ int  xs[64 * 25];
  __shared__ bf16 as[64 * AF_PAD];
  const int b0 = blockIdx.x * 64;
  for (int i = threadIdx.x; i < 64 * 25; i += 256) xs[i] = x[(long)b0 * 25 + i];
  __syncthreads();

  const int wave = threadIdx.x >> 6, lane = threadIdx.x & 63;
  for (int role = wave; role < 18; role += 4) {
    if (role < 17) {
      const int c = role;
      float acc[25];
      #pragma unroll
      for (int m = 0; m < 25; m++) acc[m] = 0.f;
      #pragma unroll
      for (int l = 0; l < 25; l++) {
        int xl = xs[lane * 25 + l];
        if (xl == c) {
          #pragma unroll
          for (int m = 0; m < 25; m++) acc[m] += W_df[c * 625 + m * 25 + l];
        }
      }
      #pragma unroll
      for (int m = 0; m < 25; m++)
        as[lane * AF_PAD + c * 25 + m] = (bf16)lrelu(acc[m] + b_df[c * 25 + m]);
    } else {
      for (int k = 425; k < 448; k++) as[lane * AF_PAD + k] = (bf16)0.f;
    }
  }
  __syncthreads();

  // coalesced copy-out: 64 rows x 448 bf16 = 3584 x int4
  int4* dst = (int4*)(a_full + (long)b0 * 448);
  for (int i = threadIdx.x; i < 3584; i += 256) {
    int row = i / 56, off = i % 56;  // 56 int4 per row
    dst[i] = *(const int4*)((const char*)as + row * (AF_PAD * 2) + off * 16);
  }
}

// ---------------------------------------------------------------------------
// hv_kernel: hori/vert branches via U tables. One wave per sample, lane = o.
// ---------------------------------------------------------------------------
__device__ __forceinline__ float group5(const float* __restrict__ U, int lane,
                                        int c0, int c1, int c2, int c3, int c4) {
  float acc = U[lane];  // base slot [0][0][lane]
  {
    int m = 1 | ((int)(c1 == c0) << 1) | ((int)(c2 == c0) << 2) |
                ((int)(c3 == c0) << 3) | ((int)(c4 == c0) << 4);
    acc += U[(c0 * 32 + m) * 64 + lane];
  }
  if (c1 != c0) {
    int m = 2 | ((int)(c2 == c1) << 2) | ((int)(c3 == c1) << 3) | ((int)(c4 == c1) << 4);
    acc += U[(c1 * 32 + m) * 64 + lane];
  }
  if (c2 != c0 && c2 != c1) {
    int m = 4 | ((int)(c3 == c2) << 3) | ((int)(c4 == c2) << 4);
    acc += U[(c2 * 32 + m) * 64 + lane];
  }
  if (c3 != c0 && c3 != c1 && c3 != c2) {
    int m = 8 | ((int)(c4 == c3) << 4);
    acc += U[(c3 * 32 + m) * 64 + lane];
  }
  if (c4 != c0 && c4 != c1 && c4 != c2 && c4 != c3) {
    acc += U[(c4 * 32 + 16) * 64 + lane];
  }
  return lrelu(acc);
}

__global__ __launch_bounds__(256) void hv_kernel(
    const int* __restrict__ x, const float* __restrict__ Uh,
    const float* __restrict__ Uv, bf16* __restrict__ cat) {
  const int wave = threadIdx.x >> 6, lane = threadIdx.x & 63;
  const long b = (long)blockIdx.x * 4 + wave;
  const int* xb = x + b * 25;
  int xv[25];
  #pragma unroll
  for (int i = 0; i < 25; i++) xv[i] = xb[i];
  bf16* catb = cat + b * 960;
  #pragma unroll
  for (int r = 0; r < 5; r++) {
    float v = group5(Uh, lane, xv[5*r], xv[5*r+1], xv[5*r+2], xv[5*r+3], xv[5*r+4]);
    catb[320 + r * 64 + lane] = (bf16)v;  // coalesced across lanes
  }
  #pragma unroll
  for (int j = 0; j < 5; j++) {
    float v = group5(Uv, lane, xv[j], xv[5+j], xv[10+j], xv[15+j], xv[20+j]);
    catb[640 + j * 64 + lane] = (bf16)v;
  }
}

// ---------------------------------------------------------------------------
// gemm_bt: C[M,N] = lrelu(A[M,KT] @ Bt[N,KT]^T + bias), m97-style structure:
// 128x128 tile, BK=32, 4 waves x (4x4) 16x16x32 bf16 MFMA frags,
// global_load_lds width-16 staging, 2-barrier K-loop.
// MODE 0: bf16 out (cat, G1).  MODE 1: f32 out (final, G2).
// R1: blockIdx -> (mt,nt) via chunk-contiguous XCD swizzle.
// ---------------------------------------------------------------------------
template <int KT, int MODE>
__global__ __launch_bounds__(256, 2) void gemm_bt(
    const bf16* __restrict__ A, const bf16* __restrict__ Bt,
    const float* __restrict__ bias, bf16* __restrict__ outb,
    float* __restrict__ outf, const int Nwrite, const int ldOut) {
  static_assert(KT % 32 == 0, "KT must be multiple of 32");
  __shared__ bf16 As[128 * 32];
  __shared__ bf16 Bs[128 * 32];

  const int tid = threadIdx.x;
  const int wave = tid >> 6, lane = tid & 63;
  int mt, nt;
  xcd_remap(mt, nt);

  // staging: wave covers 32 rows (2 instrs of 16 rows); lane -> (row=lane/4, 16B chunk=lane%4)
  const int  lrow = lane >> 2, lcol = lane & 3;
  const bf16* ag0 = A  + ((long)mt * 128 + wave * 32 + lrow) * KT + lcol * 8;
  const bf16* bg0 = Bt + ((long)nt * 128 + wave * 32 + lrow) * KT + lcol * 8;
  bf16* al = &As[(wave * 32 + lrow) * 32 + lcol * 8];  // = wave base + lane*16B
  bf16* bl = &Bs[(wave * 32 + lrow) * 32 + lcol * 8];

  const int wm = (wave & 1) * 64;   // wave's 64x64 sub-tile
  const int wn = (wave >> 1) * 64;
  const int fr = lane & 15;         // frag row (A) / col (B)
  const int fq = lane >> 4;         // quad -> k chunk

  f32x4 acc[4][4];
  #pragma unroll
  for (int i = 0; i < 4; i++)
    #pragma unroll
    for (int j = 0; j < 4; j++) acc[i][j] = f32x4{0.f, 0.f, 0.f, 0.f};

  for (int kt = 0; kt < KT / 32; kt++) {
    const int ko = kt * 32;
    gl2lds16(ag0 + ko, al);
    gl2lds16(ag0 + ko + (long)16 * KT, al + 16 * 32);
    gl2lds16(bg0 + ko, bl);
    gl2lds16(bg0 + ko + (long)16 * KT, bl + 16 * 32);
    __syncthreads();  // drains vmcnt before barrier

    bf16x8 af[4], bfv[4];
    #pragma unroll
    for (int i = 0; i < 4; i++)
      af[i] = *(const bf16x8*)&As[(wm + i * 16 + fr) * 32 + fq * 8];
    #pragma unroll
    for (int j = 0; j < 4; j++)
      bfv[j] = *(const bf16x8*)&Bs[(wn + j * 16 + fr) * 32 + fq * 8];
    #pragma unroll
    for (int i = 0; i < 4; i++)
      #pragma unroll
      for (int j = 0; j < 4; j++)
        acc[i][j] = __builtin_amdgcn_mfma_f32_16x16x32_bf16(af[i], bfv[j], acc[i][j], 0, 0, 0);
    __syncthreads();  // protect LDS before next staging
  }

  // epilogue: D row = wm+i*16+fq*4+r, col = wn+j*16+fr
  #pragma unroll
  for (int j = 0; j < 4; j++) {
    const int n = nt * 128 + wn + j * 16 + fr;
    const bool ok = n < Nwrite;
    const float bv = ok ? bias[n] : 0.f;
    #pragma unroll
    for (int i = 0; i < 4; i++) {
      const long row0 = (long)mt * 128 + wm + i * 16 + fq * 4;
      #pragma unroll
      for (int r = 0; r < 4; r++) {
        float v = lrelu(acc[i][j][r] + bv);
        if (ok) {
          if (MODE == 0) outb[(row0 + r) * (long)ldOut + n] = (bf16)v;
          else           outf[(row0 + r) * (long)ldOut + n] = v;
        }
      }
    }
  }
}

// ---------------------------------------------------------------------------
extern "C" void kernel_launch(void* const* d_in, const int* in_sizes, int n_in,
                              void* d_out, int out_size, void* d_ws, size_t ws_size,
                              hipStream_t stream) {
  const int*   x     = (const int*)d_in[0];
  const float* W_df  = (const float*)d_in[1];
  const float* b_df  = (const float*)d_in[2];
  const float* W_pf  = (const float*)d_in[3];
  const float* b_pf  = (const float*)d_in[4];
  const float* W_dh  = (const float*)d_in[5];
  const float* b_dh  = (const float*)d_in[6];
  const float* W_ph  = (const float*)d_in[7];
  const float* b_ph  = (const float*)d_in[8];
  const float* W_dv  = (const float*)d_in[9];
  const float* b_dv  = (const float*)d_in[10];
  const float* W_pv  = (const float*)d_in[11];
  const float* b_pv  = (const float*)d_in[12];
  const float* W_out = (const float*)d_in[13];
  const float* b_out = (const float*)d_in[14];
  float* out = (float*)d_out;

  const int B = in_sizes[0] / 25;  // 65536

  char* ws = (char*)d_ws;
  size_t off = 0;
  bf16* cat   = (bf16*)(ws + off); off += (size_t)B * 960 * 2;
  bf16* afull = (bf16*)(ws + off); off += (size_t)B * 448 * 2;
  bf16* WbOT  = (bf16*)(ws + off); off += (size_t)1664 * 960 * 2;
  bf16* WbPF  = (bf16*)(ws + off); off += (size_t)384 * 448 * 2;
  float* Uh   = (float*)(ws + off); off += (size_t)17 * 32 * 64 * 4;
  float* Uv   = (float*)(ws + off); off += (size_t)17 * 32 * 64 * 4;

  const int prep_threads = 1664 * 960 + 384 * 448 + 2 * 17 * 32 * 64;
  prep_kernel<<<(prep_threads + 255) / 256, 256, 0, stream>>>(
      W_pf, W_dh, b_dh, W_ph, b_ph, W_dv, b_dv, W_pv, b_pv, W_out,
      WbOT, WbPF, Uh, Uv);

  build_afull<<<B / 64, 256, 0, stream>>>(x, W_df, b_df, afull);

  gemm_bt<448, 0><<<dim3(3, B / 128), 256, 0, stream>>>(
      afull, WbPF, b_pf, cat, nullptr, 320, 960);

  hv_kernel<<<B / 4, 256, 0, stream>>>(x, Uh, Uv, cat);

  gemm_bt<960, 1><<<dim3(13, B / 128), 256, 0, stream>>>(
      cat, WbOT, b_out, nullptr, out, 1600, 1600);
}